// Round 9
// baseline (269.898 us; speedup 1.0000x reference)
//
#include <hip/hip_runtime.h>
#include <cstdint>
#include <cstddef>

typedef __bf16 bf16_t;
typedef bf16_t bf16x4 __attribute__((ext_vector_type(4)));
typedef bf16_t bf16x8 __attribute__((ext_vector_type(8)));
typedef float f32x4 __attribute__((ext_vector_type(4)));

// async global->LDS, 16B per lane; LDS dest = wave-uniform base + lane*16
static __device__ __forceinline__ void glds16(const void* g, void* l) {
    __builtin_amdgcn_global_load_lds((const __attribute__((address_space(1))) void*)g,
                                     (__attribute__((address_space(3))) void*)l,
                                     16, 0, 0);
}

#define BARRIER()  asm volatile("s_barrier" ::: "memory")
#define DS_WAIT()  do { asm volatile("s_waitcnt lgkmcnt(0)" ::: "memory"); \
                        __builtin_amdgcn_sched_barrier(0); } while (0)

// ---------------------------------------------------------------------------
// One-shot fp32 -> bf16 cast of the five GEMM operands. 1024 elts / block.
// ---------------------------------------------------------------------------
__global__ __launch_bounds__(256)
void cast5(const float* __restrict__ s0, bf16_t* __restrict__ d0, int n0,
           const float* __restrict__ s1, bf16_t* __restrict__ d1, int n1,
           const float* __restrict__ s2, bf16_t* __restrict__ d2, int n2,
           const float* __restrict__ s3, bf16_t* __restrict__ d3, int n3,
           const float* __restrict__ s4, bf16_t* __restrict__ d4)
{
    int bb = blockIdx.x;
    const float* s; bf16_t* d;
    if (bb < n0)              { s = s0; d = d0; }
    else if ((bb -= n0) < n1) { s = s1; d = d1; }
    else if ((bb -= n1) < n2) { s = s2; d = d2; }
    else if ((bb -= n2) < n3) { s = s3; d = d3; }
    else                      { bb -= n3; s = s4; d = d4; }
    const size_t base = (size_t)bb * 1024 + threadIdx.x * 4;
    const f32x4 v = *(const f32x4*)(s + base);
    bf16x4 o;
    o[0] = (bf16_t)v[0]; o[1] = (bf16_t)v[1]; o[2] = (bf16_t)v[2]; o[3] = (bf16_t)v[3];
    *(bf16x4*)(d + base) = o;
}

// ---------------------------------------------------------------------------
// 256x256-tile 8-wave deep-pipelined GEMM (T2+T3+T4+T5 stack), 3-phase/K-tile.
// R2-proven schedule: ds-reads FIRST, stage-prefetch late in phase, boundary
// vmcnt AFTER the P3 MFMA cluster. Do not reorder (R3 regression: -34%).
// ---------------------------------------------------------------------------
#define LOAD_A(MQ) \
    _Pragma("unroll") for (int mf = 0; mf < 4; ++mf) { \
        aF[mf][0] = *(const bf16x8*)(Ab + (aRow + (MQ)*64 + mf*16)*64 + ck0); \
        aF[mf][1] = *(const bf16x8*)(Ab + (aRow + (MQ)*64 + mf*16)*64 + ck1); }

#define LOAD_B(NQ, dst) \
    _Pragma("unroll") for (int nf = 0; nf < 2; ++nf) { \
        dst[nf][0] = *(const bf16x8*)(Bb + (bRow + (NQ)*32 + nf*16)*64 + ck0); \
        dst[nf][1] = *(const bf16x8*)(Bb + (bRow + (NQ)*32 + nf*16)*64 + ck1); }

#define MFMA16(MQ, NQ, bset) \
    __builtin_amdgcn_s_setprio(1); \
    _Pragma("unroll") for (int mf = 0; mf < 4; ++mf) \
    _Pragma("unroll") for (int nf = 0; nf < 2; ++nf) \
    _Pragma("unroll") for (int kk = 0; kk < 2; ++kk) \
        acc[(MQ)*4+mf][(NQ)*2+nf] = __builtin_amdgcn_mfma_f32_16x16x32_bf16( \
            aF[mf][kk], bset[nf][kk], acc[(MQ)*4+mf][(NQ)*2+nf], 0, 0, 0); \
    __builtin_amdgcn_s_setprio(0);

template<int EPI, int SPLITK>
__global__ __launch_bounds__(512, 2)
void gemm256_bt(const bf16_t* __restrict__ A, const bf16_t* __restrict__ Bt,
                const int N, const int K, const int KC,
                bf16_t* __restrict__ o0, bf16_t* __restrict__ o1)
{
    constexpr int TILE = 256 * 64;
    __shared__ __align__(16) bf16_t As[2 * TILE];
    __shared__ __align__(16) bf16_t Bs[2 * TILE];

    const int tid  = threadIdx.x;
    const int lane = tid & 63;
    const int w    = tid >> 6;                 // wave 0..7
    const int wm   = w >> 2, wn = w & 3;       // 2M x 4N wave grid
    const int l16  = lane & 15, quad = lane >> 4;
    const int e7   = l16 & 7;
    const int ck0  = (quad ^ e7) << 3;         // swizzled col (elems), kk=0
    const int ck1  = ck0 ^ 32;                 // kk=1
    const int lr   = lane >> 3, l8 = lane & 7; // staging lane decomposition
    const int swz  = (l8 ^ lr) << 3;           // pre-swizzled global col
    const int m0   = blockIdx.y * 256, n0 = blockIdx.x * 256;
    const int NT   = KC >> 6;

    const int aRow = wm * 128 + l16;
    const int bRow = wn * 64 + l16;

    f32x4 acc[8][4] = {};
    bf16x8 aF[4][2], bLo[2][2], bHi[2][2];

    auto STAGE = [&](int unit, int kt, int d) {
        const bf16_t* g; int rg0; bf16_t* lb; int rbase;
        if (unit <= 1) { g = A;  rg0 = m0; lb = As;
                         rbase = unit * 64 + w * 8; }
        else           { g = Bt; rg0 = n0; lb = Bs;
                         rbase = ((w >> 2) << 6) + ((w & 3) << 3) + ((unit & 1) << 5); }
#pragma unroll
        for (int L = 0; L < 2; ++L) {
            const int rb = rbase + L * 128;
            glds16(g + (size_t)(rg0 + rb + lr) * K + kt * 64 + swz,
                   lb + d * TILE + rb * 64);
        }
    };

    // ---- prologue: tile0 complete + tile1 minus A1 (staged at iter0 P1) ----
    STAGE(2, 0, 0); STAGE(0, 0, 0); STAGE(3, 0, 0); STAGE(1, 0, 0);
    if (NT > 1) { STAGE(2, 1, 1); STAGE(0, 1, 1); STAGE(3, 1, 1); }
    if (NT > 1) asm volatile("s_waitcnt vmcnt(6)" ::: "memory");
    else        asm volatile("s_waitcnt vmcnt(0)" ::: "memory");
    BARRIER();

    for (int i = 0; i < NT; ++i) {
        const int b = i & 1;
        const bf16_t* Ab = As + b * TILE;
        const bf16_t* Bb = Bs + b * TILE;

        // P1: (mlo,nlo) -- load A-lo + B-lo; stage A1(i+1) -> other buf
        LOAD_A(0); LOAD_B(0, bLo);
        if (i + 1 < NT) STAGE(1, i + 1, (i + 1) & 1);
        BARRIER(); DS_WAIT();
        MFMA16(0, 0, bLo);
        __builtin_amdgcn_sched_barrier(0);
        BARRIER();

        // P2: (mlo,nhi) -- load B-hi; stage B0(i+2) -> this buf
        LOAD_B(1, bHi);
        if (i + 2 < NT) STAGE(2, i + 2, b);
        BARRIER(); DS_WAIT();
        MFMA16(0, 1, bHi);
        __builtin_amdgcn_sched_barrier(0);
        BARRIER();

        // P3: (mhi,*) -- load A-hi; stage A0(i+2),B1(i+2); 32 MFMA; boundary
        // vmcnt AFTER the cluster (shadowed), just before the barrier.
        LOAD_A(1);
        if (i + 2 < NT) { STAGE(0, i + 2, b); STAGE(3, i + 2, b); }
        BARRIER(); DS_WAIT();
        MFMA16(1, 1, bHi);
        MFMA16(1, 0, bLo);
        __builtin_amdgcn_sched_barrier(0);
        if (i + 2 < NT) asm volatile("s_waitcnt vmcnt(6)" ::: "memory");
        else            asm volatile("s_waitcnt vmcnt(0)" ::: "memory");
        BARRIER();
    }

    // ---- epilogue: C/D layout col = lane&15, row = quad*4 + reg ----
#pragma unroll
    for (int mf = 0; mf < 8; ++mf)
#pragma unroll
        for (int nf = 0; nf < 4; ++nf)
#pragma unroll
            for (int r = 0; r < 4; ++r) {
                const int gr = m0 + wm * 128 + mf * 16 + quad * 4 + r;
                const int gc = n0 + wn * 64 + nf * 16 + l16;
                const float v = acc[mf][nf][r];
                if (EPI == 1) {
                    if (gc < 2048) o0[(size_t)gr * 2048 + gc] = (bf16_t)v;
                    else           o1[(size_t)gr * 2048 + (gc - 2048)] = (bf16_t)v;
                } else {
                    ((float*)o0)[(size_t)gr * N + gc] = v;
                }
            }
}

// ---------------------------------------------------------------------------
// out_proj GEMM: 64x64 tiles, direct fp32 write. 1024 blocks = 4 blocks/CU
// (the 2-barrier structure's measured operating point). No split-K/atomics.
// ---------------------------------------------------------------------------
__global__ __launch_bounds__(256)
void gemm64(const bf16_t* __restrict__ A, const bf16_t* __restrict__ Bt,
            const int N, const int K, float* __restrict__ out)
{
    __shared__ __align__(16) bf16_t As[64 * 64];
    __shared__ __align__(16) bf16_t Bs[64 * 64];

    const int tid  = threadIdx.x;
    const int lane = tid & 63;
    const int wave = tid >> 6;
    const int wm = wave & 1, wn = wave >> 1;   // 2M x 2N wave grid
    const int m0 = blockIdx.y * 64, n0 = blockIdx.x * 64;
    const int quad = lane >> 4, l16 = lane & 15;

    f32x4 acc[2][2] = {};

    for (int k0 = 0; k0 < K; k0 += 64) {
        __syncthreads();
#pragma unroll
        for (int j = 0; j < 2; j++) {
            const int u  = j * 2048 + wave * 512;   // wave-uniform LDS elem base
            const int ue = u + lane * 8;            // per-lane element index
            const int row = ue >> 6, col = ue & 63;
            glds16(A  + (size_t)(m0 + row) * K + k0 + col, As + u);
            glds16(Bt + (size_t)(n0 + row) * K + k0 + col, Bs + u);
        }
        __syncthreads();

#pragma unroll
        for (int kk = 0; kk < 2; kk++) {
            bf16x8 afr[2], bfr[2];
#pragma unroll
            for (int mt = 0; mt < 2; mt++)
                afr[mt] = *(const bf16x8*)(As + (wm * 32 + mt * 16 + l16) * 64 + kk * 32 + quad * 8);
#pragma unroll
            for (int nt = 0; nt < 2; nt++)
                bfr[nt] = *(const bf16x8*)(Bs + (wn * 32 + nt * 16 + l16) * 64 + kk * 32 + quad * 8);
#pragma unroll
            for (int mt = 0; mt < 2; mt++)
#pragma unroll
                for (int nt = 0; nt < 2; nt++)
                    acc[mt][nt] = __builtin_amdgcn_mfma_f32_16x16x32_bf16(
                        afr[mt], bfr[nt], acc[mt][nt], 0, 0, 0);
        }
    }

    // C/D layout (m89-verified): col = lane&15, row = quad*4 + reg
#pragma unroll
    for (int mt = 0; mt < 2; mt++)
#pragma unroll
        for (int nt = 0; nt < 2; nt++)
#pragma unroll
            for (int r = 0; r < 4; r++) {
                const int gr = m0 + wm * 32 + mt * 16 + quad * 4 + r;
                const int gc = n0 + wn * 32 + nt * 16 + l16;
                out[(size_t)gr * N + gc] = acc[mt][nt][r];
            }
}

// ---------------------------------------------------------------------------
// GEMM: 128x128 tile, 2-barrier structure. (fallback dt_proj EPI 2 only)
// ---------------------------------------------------------------------------
template<int EPI, int SPLITK>
__global__ __launch_bounds__(256)
void gemm_bt(const bf16_t* __restrict__ A, const bf16_t* __restrict__ Bt,
             const int M, const int N, const int K,
             void* __restrict__ o0, void* __restrict__ o1,
             const float* __restrict__ bias)
{
    __shared__ __align__(16) bf16_t As[128 * 64];
    __shared__ __align__(16) bf16_t Bs[128 * 64];

    const int tid  = threadIdx.x;
    const int lane = tid & 63;
    const int wave = tid >> 6;
    const int wm = wave & 1, wn = wave >> 1;
    const int m0 = blockIdx.y * 128, n0 = blockIdx.x * 128;
    const int quad = lane >> 4, l16 = lane & 15;
    const int z   = (SPLITK > 1) ? blockIdx.z : 0;
    const int KC  = K / SPLITK;
    const int kb  = z * KC;

    f32x4 acc[4][4] = {};

    for (int k0 = kb; k0 < kb + KC; k0 += 64) {
        __syncthreads();
#pragma unroll
        for (int j = 0; j < 4; j++) {
            const int u  = wave * 2048 + j * 512;   // wave-uniform LDS elem base
            const int ue = u + lane * 8;            // per-lane element index
            const int row = ue >> 6, col = ue & 63;
            glds16(A  + (size_t)(m0 + row) * K + k0 + col, As + u);
            glds16(Bt + (size_t)(n0 + row) * K + k0 + col, Bs + u);
        }
        __syncthreads();

#pragma unroll
        for (int kk = 0; kk < 2; kk++) {
            bf16x8 afr[4], bfr[4];
#pragma unroll
            for (int mt = 0; mt < 4; mt++)
                afr[mt] = *(const bf16x8*)(As + (wm * 64 + mt * 16 + l16) * 64 + kk * 32 + quad * 8);
#pragma unroll
            for (int nt = 0; nt < 4; nt++)
                bfr[nt] = *(const bf16x8*)(Bs + (wn * 64 + nt * 16 + l16) * 64 + kk * 32 + quad * 8);
#pragma unroll
            for (int mt = 0; mt < 4; mt++)
#pragma unroll
                for (int nt = 0; nt < 4; nt++)
                    acc[mt][nt] = __builtin_amdgcn_mfma_f32_16x16x32_bf16(
                        afr[mt], bfr[nt], acc[mt][nt], 0, 0, 0);
        }
    }

    // C/D layout (m89-verified): col = lane&15, row = quad*4 + reg
#pragma unroll
    for (int mt = 0; mt < 4; mt++)
#pragma unroll
        for (int nt = 0; nt < 4; nt++)
#pragma unroll
            for (int r = 0; r < 4; r++) {
                const int gr = m0 + wm * 64 + mt * 16 + quad * 4 + r;
                const int gc = n0 + wn * 64 + nt * 16 + l16;
                const float v = acc[mt][nt][r];
                if (EPI == 2) {
                    const float t  = v + bias[gc];
                    const float sp = (t > 15.f) ? t : __logf(1.f + __expf(t));
                    ((bf16_t*)o0)[(size_t)gr * 2048 + gc] = (bf16_t)sp;
                } else {
                    ((float*)o0)[(size_t)gr * N + gc] = v;
                }
            }
}

// ---------------------------------------------------------------------------
// FUSED conv+silu -> x_proj -> dt_proj(+softplus). One block = 16 token rows.
// LOW-LDS variant: no xsL staging buffer (64KB) -- x_proj's A operand is
// re-read from GLOBAL xs (the block's own 16 just-written rows; visible via
// __syncthreads' workgroup-scope fence; L2-hot). LDS 93 -> ~28KB lifts
// residency 1 -> ~3 blocks/CU so the serial conv->GEMM->reduce->GEMM chain
// gets cross-block latency hiding (R6 profile: Occ 9.7%, MfmaUtil 1.7%).
// ---------------------------------------------------------------------------
__global__ __launch_bounds__(256)
void conv_xproj_dt(const bf16_t* __restrict__ xs_pre,
                   const float* __restrict__ cw, const float* __restrict__ cb,
                   const bf16_t* __restrict__ Wxp, const bf16_t* __restrict__ Wdt,
                   const float* __restrict__ bdt,
                   bf16_t* __restrict__ xs, bf16_t* __restrict__ dt,
                   float* __restrict__ Bm, float* __restrict__ Cm)
{
    __shared__ float red[4][64][25];
    __shared__ __align__(16) bf16_t dtA[16 * 64];     // [row][col], swizzled

    const int tid  = threadIdx.x;
    const int lane = tid & 63, w = tid >> 6;
    const int m0   = blockIdx.x * 16;
    const int l16  = lane & 15, quad = lane >> 4, l8 = lane & 7;
    const int l0   = m0 & 2047;                       // sequence-local base

    // ---- conv + silu: rows m0..m0+15, this thread's 8 channels ----
    {
        const int d0 = tid * 8;
        float w0[8], w1[8], w2[8], w3[8], bs[8];
#pragma unroll
        for (int j = 0; j < 8; j++) {
            const f32x4 wv = *(const f32x4*)(cw + (size_t)(d0 + j) * 4);
            w0[j] = wv[0]; w1[j] = wv[1]; w2[j] = wv[2]; w3[j] = wv[3];
            bs[j] = cb[d0 + j];
        }
        const int r1 = (m0 >= 1) ? m0 - 1 : 0;
        const int r2 = (m0 >= 2) ? m0 - 2 : 0;
        const int r3 = (m0 >= 3) ? m0 - 3 : 0;
        const bf16x8 v1 = *(const bf16x8*)(xs_pre + (size_t)r1 * 2048 + d0);
        const bf16x8 v2 = *(const bf16x8*)(xs_pre + (size_t)r2 * 2048 + d0);
        const bf16x8 v3 = *(const bf16x8*)(xs_pre + (size_t)r3 * 2048 + d0);
        float p1[8], p2[8], p3[8];
#pragma unroll
        for (int j = 0; j < 8; j++) {
            p1[j] = (float)v1[j]; p2[j] = (float)v2[j]; p3[j] = (float)v3[j];
        }
#pragma unroll
        for (int r = 0; r < 16; r++) {
            const int l = l0 + r;
            const float m1 = (l >= 1) ? 1.f : 0.f;
            const float m2 = (l >= 2) ? 1.f : 0.f;
            const float m3 = (l >= 3) ? 1.f : 0.f;
            const bf16x8 v = *(const bf16x8*)(xs_pre + (size_t)(m0 + r) * 2048 + d0);
            bf16x8 o;
#pragma unroll
            for (int j = 0; j < 8; j++) {
                const float cur = (float)v[j];
                float a = bs[j] + w3[j] * cur;
                a += m1 * w2[j] * p1[j];
                a += m2 * w1[j] * p2[j];
                a += m3 * w0[j] * p3[j];
                const float s = a / (1.f + __expf(-a));
                o[j] = (bf16_t)s;
                p3[j] = p2[j]; p2[j] = p1[j]; p1[j] = cur;
            }
            *(bf16x8*)(xs + (size_t)(m0 + r) * 2048 + d0) = o;
        }
    }
    __syncthreads();   // conv writes visible block-wide (workgroup fence)

    // ---- GEMM1 (x_proj): 4-wave split-K over 2048; A from GLOBAL xs ----
    f32x4 acc[6] = {};
    const int kbase = w * 512;
    const bf16_t* ap = xs + (size_t)(m0 + l16) * 2048 + kbase + quad * 8;
    for (int k0 = 0; k0 < 512; k0 += 32) {
        const bf16x8 afr = *(const bf16x8*)(ap + k0);
#pragma unroll
        for (int t = 0; t < 6; t++) {
            const bf16x8 bfr = *(const bf16x8*)(Wxp + (size_t)(t * 16 + l16) * 2048 + kbase + k0 + quad * 8);
            acc[t] = __builtin_amdgcn_mfma_f32_16x16x32_bf16(afr, bfr, acc[t], 0, 0, 0);
        }
    }
#pragma unroll
    for (int t = 0; t < 6; t++)
#pragma unroll
        for (int r = 0; r < 4; r++) red[w][lane][t * 4 + r] = acc[t][r];
    __syncthreads();

    // ---- reduce: wave w builds dtA cols [w*16, +16); wave 0 writes Bm/Cm ----
    {
#pragma unroll
        for (int r = 0; r < 4; r++) {
            const int j = w * 4 + r;
            const float v = red[0][lane][j] + red[1][lane][j]
                          + red[2][lane][j] + red[3][lane][j];
            const int row = quad * 4 + r, col = w * 16 + l16;
            const int g = (col >> 3) ^ (row & 7);
            dtA[row * 64 + g * 8 + (col & 7)] = (bf16_t)v;
        }
        if (w == 0) {
#pragma unroll
            for (int t = 4; t < 6; t++)
#pragma unroll
                for (int r = 0; r < 4; r++) {
                    const int j = t * 4 + r;
                    const float v = red[0][lane][j] + red[1][lane][j]
                                  + red[2][lane][j] + red[3][lane][j];
                    const int gr = m0 + quad * 4 + r;
                    const int gc = t * 16 + l16;
                    if (gc < 80) Bm[(size_t)gr * 16 + (gc - 64)] = v;
                    else         Cm[(size_t)gr * 16 + (gc - 80)] = v;
                }
        }
    }
    __syncthreads();

    // ---- GEMM2 (dt_proj, K=64) + softplus; wave w covers cols [w*512,+512) --
    const bf16x8 a0 = *(const bf16x8*)(dtA + l16 * 64 + (((0 + quad) ^ l8) << 3));
    const bf16x8 a1 = *(const bf16x8*)(dtA + l16 * 64 + (((4 + quad) ^ l8) << 3));
    for (int nt = 0; nt < 32; ++nt) {
        const int nb = w * 512 + nt * 16;
        const bf16x8 b0 = *(const bf16x8*)(Wdt + (size_t)(nb + l16) * 64 + quad * 8);
        const bf16x8 b1 = *(const bf16x8*)(Wdt + (size_t)(nb + l16) * 64 + 32 + quad * 8);
        f32x4 a = {};
        a = __builtin_amdgcn_mfma_f32_16x16x32_bf16(a0, b0, a, 0, 0, 0);
        a = __builtin_amdgcn_mfma_f32_16x16x32_bf16(a1, b1, a, 0, 0, 0);
        const int gc = nb + l16;
        const float bv = bdt[gc];
#pragma unroll
        for (int r = 0; r < 4; r++) {
            const int gr = m0 + quad * 4 + r;
            const float t  = a[r] + bv;
            const float sp = (t > 15.f) ? t : __logf(1.f + __expf(t));
            dt[(size_t)gr * 2048 + gc] = (bf16_t)sp;
        }
    }
}

// ---------------------------------------------------------------------------
// Causal depthwise conv (k=4) + SiLU, vectorized. (fallback path only)
// ---------------------------------------------------------------------------
__global__ __launch_bounds__(256)
void conv_silu(const bf16_t* __restrict__ xs_pre, const float* __restrict__ cw,
               const float* __restrict__ cb, bf16_t* __restrict__ xs)
{
    const int d0 = threadIdx.x * 8;
    const int rg = blockIdx.x * 8;
    float w0[8], w1[8], w2[8], w3[8], bs[8];
#pragma unroll
    for (int j = 0; j < 8; j++) {
        const f32x4 wv = *(const f32x4*)(cw + (size_t)(d0 + j) * 4);
        w0[j] = wv[0]; w1[j] = wv[1]; w2[j] = wv[2]; w3[j] = wv[3];
        bs[j] = cb[d0 + j];
    }
    float p1[8], p2[8], p3[8];
    {
        const int r1 = (rg >= 1) ? rg - 1 : 0;
        const int r2 = (rg >= 2) ? rg - 2 : 0;
        const int r3 = (rg >= 3) ? rg - 3 : 0;
        const bf16x8 v1 = *(const bf16x8*)(xs_pre + (size_t)r1 * 2048 + d0);
        const bf16x8 v2 = *(const bf16x8*)(xs_pre + (size_t)r2 * 2048 + d0);
        const bf16x8 v3 = *(const bf16x8*)(xs_pre + (size_t)r3 * 2048 + d0);
#pragma unroll
        for (int j = 0; j < 8; j++) {
            p1[j] = (float)v1[j]; p2[j] = (float)v2[j]; p3[j] = (float)v3[j];
        }
    }
#pragma unroll
    for (int t = 0; t < 8; t++) {
        const int r = rg + t;
        const int l = r & 2047;
        const float m1 = (l >= 1) ? 1.f : 0.f;
        const float m2 = (l >= 2) ? 1.f : 0.f;
        const float m3 = (l >= 3) ? 1.f : 0.f;
        const bf16x8 v = *(const bf16x8*)(xs_pre + (size_t)r * 2048 + d0);
        bf16x8 o;
#pragma unroll
        for (int j = 0; j < 8; j++) {
            const float cur = (float)v[j];
            float a = bs[j] + w3[j] * cur;
            a += m1 * w2[j] * p1[j];
            a += m2 * w1[j] * p2[j];
            a += m3 * w0[j] * p3[j];
            const float s = a / (1.f + __expf(-a));
            o[j] = (bf16_t)s;
            p3[j] = p2[j]; p2[j] = p1[j]; p1[j] = cur;
        }
        *(bf16x8*)(xs + (size_t)r * 2048 + d0) = o;
    }
}

// ---------------------------------------------------------------------------
// x_proj standalone (fallback path only).
// ---------------------------------------------------------------------------
__global__ __launch_bounds__(256)
void xproj_kernel(const bf16_t* __restrict__ A, const bf16_t* __restrict__ Bt,
                  bf16_t* __restrict__ dtr, float* __restrict__ Bm, float* __restrict__ Cm)
{
    __shared__ float red[4][64][25];
    const int tid  = threadIdx.x;
    const int lane = tid & 63, w = tid >> 6;
    const int m0 = blockIdx.x * 16;
    const int l16 = lane & 15, quad = lane >> 4;
    f32x4 acc[6] = {};

    const int kbase = w * 512;
    const bf16_t* ap = A + (size_t)(m0 + l16) * 2048 + kbase + quad * 8;
    for (int k0 = 0; k0 < 512; k0 += 32) {
        const bf16x8 afr = *(const bf16x8*)(ap + k0);
#pragma unroll
        for (int t = 0; t < 6; t++) {
            const bf16x8 bfr = *(const bf16x8*)(Bt + (size_t)(t * 16 + l16) * 2048 + kbase + k0 + quad * 8);
            acc[t] = __builtin_amdgcn_mfma_f32_16x16x32_bf16(afr, bfr, acc[t], 0, 0, 0);
        }
    }
#pragma unroll
    for (int t = 0; t < 6; t++)
#pragma unroll
        for (int r = 0; r < 4; r++) red[w][lane][t * 4 + r] = acc[t][r];
    __syncthreads();
    if (w == 0) {
#pragma unroll
        for (int t = 0; t < 6; t++)
#pragma unroll
            for (int r = 0; r < 4; r++) {
                const int j = t * 4 + r;
                const float v = red[0][lane][j] + red[1][lane][j]
                              + red[2][lane][j] + red[3][lane][j];
                const int gr = m0 + quad * 4 + r;
                const int gc = t * 16 + l16;
                if (gc < 64)      dtr[(size_t)gr * 64 + gc] = (bf16_t)v;
                else if (gc < 80) Bm[(size_t)gr * 16 + (gc - 64)] = v;
                else              Cm[(size_t)gr * 16 + (gc - 80)] = v;
            }
    }
}

// ---------------------------------------------------------------------------
// Register-state chunked scan. Row-major dt/xs: scalar per-thread loads are
// wave-coalesced (lane i -> channel d+i, consecutive 2B addresses).
// ---------------------------------------------------------------------------
static __device__ __forceinline__ bool fast_check(const float* A_log, int d, float& a1) {
    a1 = -__expf(A_log[(size_t)d * 16]);
    bool ok = true;
#pragma unroll
    for (int n = 1; n < 16; n++) {
        const float an = -__expf(A_log[(size_t)d * 16 + n]);
        const float pn = (float)(n + 1) * a1;
        ok = ok && (fabsf(an - pn) <= 1e-3f * fabsf(pn) + 1e-6f);
    }
    return ok;
}

__global__ __launch_bounds__(256)
void scan1(const bf16_t* __restrict__ dt, const bf16_t* __restrict__ xs,
           const float* __restrict__ Bm, const float* __restrict__ A_log,
           float* __restrict__ sdt_o, bf16_t* __restrict__ Hsum)
{
    const int tid = threadIdx.x;
    const int bi  = blockIdx.x;
    const int c   = bi & 63;
    const int bb  = bi >> 6;
    const int b   = bb >> 3;
    const int d   = (bb & 7) * 256 + tid;
    float a1; const bool fast = fast_check(A_log, d, a1);

    float h[16] = {};
    float s = 0.f;
    const size_t rowbase = (size_t)b * 2048 + c * 32;

    if (fast) {
#pragma unroll 4
        for (int t = 0; t < 32; t++) {
            const size_t ro = (rowbase + t) * 2048 + d;
            const float dtv = (float)dt[ro];
            const float xv  = (float)xs[ro];
            s += dtv;
            const float r = __expf(dtv * a1);
            float rp[16]; rp[0] = r;
#pragma unroll
            for (int n = 1; n < 16; n++) rp[n] = rp[n - 1] * r;
            const float bx = dtv * xv;
            const float* bp = Bm + (rowbase + t) * 16;
#pragma unroll
            for (int n = 0; n < 16; n++) h[n] = fmaf(h[n], rp[n], bx * bp[n]);
        }
    } else {
        for (int t = 0; t < 32; t++) {
            const size_t ro = (rowbase + t) * 2048 + d;
            const float dtv = (float)dt[ro];
            const float xv  = (float)xs[ro];
            s += dtv;
            const float bx = dtv * xv;
            const float* bp = Bm + (rowbase + t) * 16;
#pragma unroll
            for (int n = 0; n < 16; n++) {
                const float an = -__expf(A_log[(size_t)d * 16 + n]);
                h[n] = fmaf(h[n], __expf(dtv * an), bx * bp[n]);
            }
        }
    }
    const size_t sb = (size_t)bi * 256 + tid;
    sdt_o[sb] = s;
    bf16x8 h0, h1;
#pragma unroll
    for (int n = 0; n < 8; n++) { h0[n] = (bf16_t)h[n]; h1[n] = (bf16_t)h[n + 8]; }
    *(bf16x8*)(Hsum + sb * 16)     = h0;
    *(bf16x8*)(Hsum + sb * 16 + 8) = h1;
}

// Inter-chunk exclusive scan, prefetch distance 2.
__global__ __launch_bounds__(256)
void scan2(const float* __restrict__ sdt, bf16_t* __restrict__ Hsum,
           const float* __restrict__ A_log)
{
    const int tid = threadIdx.x;
    const int bb  = blockIdx.x;
    const int d   = (bb & 7) * 256 + tid;
    float a1; const bool fast = fast_check(A_log, d, a1);

    float h[16] = {};
    if (fast) {
        size_t sb = (size_t)(bb * 64) * 256 + tid;
        float sA = sdt[sb];
        bf16x8 hA0 = *(const bf16x8*)(Hsum + sb * 16);
        bf16x8 hA1 = *(const bf16x8*)(Hsum + sb * 16 + 8);
        float sB = 0.f; bf16x8 hB0 = {}, hB1 = {};
        {
            const size_t sb1 = sb + 256;
            sB  = sdt[sb1];
            hB0 = *(const bf16x8*)(Hsum + sb1 * 16);
            hB1 = *(const bf16x8*)(Hsum + sb1 * 16 + 8);
        }
        for (int c = 0; c < 64; c++) {
            float sC = 0.f; bf16x8 hC0 = {}, hC1 = {};
            if (c + 2 < 64) {
                const size_t sb2 = sb + 512;
                sC  = sdt[sb2];
                hC0 = *(const bf16x8*)(Hsum + sb2 * 16);
                hC1 = *(const bf16x8*)(Hsum + sb2 * 16 + 8);
            }
            bf16x8 o0, o1;
#pragma unroll
            for (int n = 0; n < 8; n++) { o0[n] = (bf16_t)h[n]; o1[n] = (bf16_t)h[n + 8]; }
            *(bf16x8*)(Hsum + sb * 16)     = o0;
            *(bf16x8*)(Hsum + sb * 16 + 8) = o1;
            const float r = __expf(sA * a1);
            float rp[16]; rp[0] = r;
#pragma unroll
            for (int n = 1; n < 16; n++) rp[n] = rp[n - 1] * r;
#pragma unroll
            for (int n = 0; n < 16; n++) {
                const float hsv = (n < 8) ? (float)hA0[n] : (float)hA1[n - 8];
                h[n] = fmaf(h[n], rp[n], hsv);
            }
            sb += 256;
            sA = sB; hA0 = hB0; hA1 = hB1;
            sB = sC; hB0 = hC0; hB1 = hC1;
        }
    } else {
        for (int c = 0; c < 64; c++) {
            const size_t sb = ((size_t)(bb * 64 + c) * 256 + tid);
            const float s = sdt[sb];
            bf16x8 hs0 = *(const bf16x8*)(Hsum + sb * 16);
            bf16x8 hs1 = *(const bf16x8*)(Hsum + sb * 16 + 8);
            bf16x8 o0, o1;
#pragma unroll
            for (int n = 0; n < 8; n++) { o0[n] = (bf16_t)h[n]; o1[n] = (bf16_t)h[n + 8]; }
            *(bf16x8*)(Hsum + sb * 16)     = o0;
            *(bf16x8*)(Hsum + sb * 16 + 8) = o1;
#pragma unroll
            for (int n = 0; n < 16; n++) {
                const float an = -__expf(A_log[(size_t)d * 16 + n]);
                const float hsv = (n < 8) ? (float)hs0[n] : (float)hs1[n - 8];
                h[n] = fmaf(h[n], __expf(s * an), hsv);
            }
        }
    }
}

__global__ __launch_bounds__(256)
void scan3(const bf16_t* __restrict__ dt, const bf16_t* __restrict__ xs,
           bf16_t* __restrict__ zy,
           const float* __restrict__ Bm, const float* __restrict__ Cm,
           const float* __restrict__ A_log, const float* __restrict__ Dv,
           const bf16_t* __restrict__ Hseed)
{
    const int tid = threadIdx.x;
    const int bi  = blockIdx.x;
    const int c   = bi & 63;
    const int bb  = bi >> 6;
    const int b   = bb >> 3;
    const int d   = (bb & 7) * 256 + tid;
    float a1; const bool fast = fast_check(A_log, d, a1);
    const float Dd = Dv[d];

    const size_t sb = (size_t)bi * 256 + tid;
    const bf16x8 hs0 = *(const bf16x8*)(Hseed + sb * 16);
    const bf16x8 hs1 = *(const bf16x8*)(Hseed + sb * 16 + 8);
    float h[16];
#pragma unroll
    for (int n = 0; n < 8; n++) { h[n] = (float)hs0[n]; h[n + 8] = (float)hs1[n]; }

    const size_t rowbase = (size_t)b * 2048 + c * 32;

    if (fast) {
#pragma unroll 2
        for (int t = 0; t < 32; t++) {
            const size_t ro = (rowbase + t) * 2048 + d;
            const float dtv = (float)dt[ro];
            const float xv  = (float)xs[ro];
            const float zv  = (float)zy[ro];
            const float r = __expf(dtv * a1);
            float rp[16]; rp[0] = r;
#pragma unroll
            for (int n = 1; n < 16; n++) rp[n] = rp[n - 1] * r;
            const float bx = dtv * xv;
            const float* bp = Bm + (rowbase + t) * 16;
            const float* cp = Cm + (rowbase + t) * 16;
            float y0 = 0.f, y1 = 0.f;
#pragma unroll
            for (int n = 0; n < 16; n += 2) {
                h[n]     = fmaf(h[n],     rp[n],     bx * bp[n]);
                h[n + 1] = fmaf(h[n + 1], rp[n + 1], bx * bp[n + 1]);
                y0 = fmaf(h[n],     cp[n],     y0);
                y1 = fmaf(h[n + 1], cp[n + 1], y1);
            }
            const float yv = (y0 + y1) + xv * Dd;
            const float g  = zv / (1.f + __expf(-zv));
            zy[ro] = (bf16_t)(yv * g);
        }
    } else {
        for (int t = 0; t < 32; t++) {
            const size_t ro = (rowbase + t) * 2048 + d;
            const float dtv = (float)dt[ro];
            const float xv  = (float)xs[ro];
            const float zv  = (float)zy[ro];
            const float bx = dtv * xv;
            const float* bp = Bm + (rowbase + t) * 16;
            const float* cp = Cm + (rowbase + t) * 16;
            float y = 0.f;
#pragma unroll
            for (int n = 0; n < 16; n++) {
                const float an = -__expf(A_log[(size_t)d * 16 + n]);
                h[n] = fmaf(h[n], __expf(dtv * an), bx * bp[n]);
                y = fmaf(h[n], cp[n], y);
            }
            const float yv = y + xv * Dd;
            const float g  = zv / (1.f + __expf(-zv));
            zy[ro] = (bf16_t)(yv * g);
        }
    }
}

// ---------------------------------------------------------------------------
extern "C" void kernel_launch(void* const* d_in, const int* in_sizes, int n_in,
                              void* d_out, int out_size, void* d_ws, size_t ws_size,
                              hipStream_t stream)
{
    const float* x     = (const float*)d_in[0];  // [2,2048,1024]
    const float* W_in  = (const float*)d_in[1];  // [4096,1024]
    const float* convw = (const float*)d_in[2];  // [2048,1,4]
    const float* convb = (const float*)d_in[3];  // [2048]
    const float* W_xp  = (const float*)d_in[4];  // [96,2048]
    const float* W_dt  = (const float*)d_in[5];  // [2048,64]
    const float* b_dt  = (const float*)d_in[6];  // [2048]
    const float* A_log = (const float*)d_in[7];  // [2048,16]
    const float* Dv    = (const float*)d_in[8];  // [2048]
    const float* W_out = (const float*)d_in[9];  // [1024,2048]

    char* ws = (char*)d_ws;
    bf16_t* bufP   = (bf16_t*)(ws + 0);          // xs_pre
    bf16_t* bufZ   = (bf16_t*)(ws + 16777216);   // z -> yg in-place
    bf16_t* bufX   = (bf16_t*)(ws + 33554432);   // xs (conv out), row-major
    bf16_t* W_in_b = (bf16_t*)(ws + 33554432);   // ALIAS: dead before bufX written
    bf16_t* dtr    = (bf16_t*)(ws + 50331648);   // [4096,64] (fallback only)
    float*  Bm     = (float*)(ws + 50855936);    // [4096,16]
    float*  Cm     = (float*)(ws + 51118080);    // [4096,16]
    float*  sdt    = (float*)(ws + 51380224);    // [1024*256]
    bf16_t* Hsum   = (bf16_t*)(ws + 52428800);   // [1024*256*16]
    bf16_t* x_b    = (bf16_t*)(ws + 52428800);   // ALIAS: dead before Hsum written
    bf16_t* W_out_b= (bf16_t*)(ws + 60817408);   // [1024,2048]
    bf16_t* W_xp_b = (bf16_t*)(ws + 65011712);   // [96,2048]
    bf16_t* W_dt_b = (bf16_t*)(ws + 65404928);   // [2048,64]
    bf16_t* dtb    = (bf16_t*)(ws + 65667072);   // dt [4096][2048], 16.78 MB
    const bool fuse = (ws_size >= 82444288ull);  // dtb fits

    // 0) cast all GEMM operands fp32 -> bf16 (one fused kernel)
    cast5<<<dim3(4096 + 4096 + 2048 + 192 + 128), dim3(256), 0, stream>>>(
        x, x_b, 4096, W_in, W_in_b, 4096, W_out, W_out_b, 2048,
        W_xp, W_xp_b, 192, W_dt, W_dt_b);

    // 1) in_proj: xz = x @ W_in^T -> bufP (xs_pre), bufZ (z)  [256^2 pipeline]
    gemm256_bt<1, 1><<<dim3(16, 16), dim3(512), 0, stream>>>(
        x_b, W_in_b, 4096, 1024, 1024, bufP, bufZ);

    bf16_t* dtp = fuse ? dtb : bufP;   // where scan reads dt from
    if (fuse) {
        // 2-4) conv+silu -> xs ; x_proj -> Bm,Cm ; dt_proj+softplus -> dtb
        conv_xproj_dt<<<dim3(256), dim3(256), 0, stream>>>(
            bufP, convw, convb, W_xp_b, W_dt_b, b_dt, bufX, dtb, Bm, Cm);
    } else {
        conv_silu<<<dim3(512), dim3(256), 0, stream>>>(bufP, convw, convb, bufX);
        xproj_kernel<<<dim3(256), dim3(256), 0, stream>>>(bufX, W_xp_b, dtr, Bm, Cm);
        gemm_bt<2, 1><<<dim3(16, 32), dim3(256), 0, stream>>>(
            dtr, W_dt_b, 4096, 2048, 64, (void*)bufP, nullptr, b_dt);
    }

    // 5) register-state chunked scan + skip + gate -> bufZ in place
    scan1<<<dim3(1024), dim3(256), 0, stream>>>(dtp, bufX, Bm, A_log, sdt, Hsum);
    scan2<<<dim3(16),   dim3(256), 0, stream>>>(sdt, Hsum, A_log);
    scan3<<<dim3(1024), dim3(256), 0, stream>>>(dtp, bufX, bufZ, Bm, Cm, A_log, Dv, Hsum);

    // 6) out_proj: 64x64 tiles, 1024 blocks = 4/CU, direct fp32 write.
    gemm64<<<dim3(16, 64), dim3(256), 0, stream>>>(
        bufZ, W_out_b, 1024, 2048, (float*)d_out);
}

// Round 11
// 263.644 us; speedup vs baseline: 1.0237x; 1.0237x over previous
//
#include <hip/hip_runtime.h>
#include <cstdint>
#include <cstddef>

typedef __bf16 bf16_t;
typedef bf16_t bf16x4 __attribute__((ext_vector_type(4)));
typedef bf16_t bf16x8 __attribute__((ext_vector_type(8)));
typedef float f32x4 __attribute__((ext_vector_type(4)));

// async global->LDS, 16B per lane; LDS dest = wave-uniform base + lane*16
static __device__ __forceinline__ void glds16(const void* g, void* l) {
    __builtin_amdgcn_global_load_lds((const __attribute__((address_space(1))) void*)g,
                                     (__attribute__((address_space(3))) void*)l,
                                     16, 0, 0);
}

#define BARRIER()  asm volatile("s_barrier" ::: "memory")
#define DS_WAIT()  do { asm volatile("s_waitcnt lgkmcnt(0)" ::: "memory"); \
                        __builtin_amdgcn_sched_barrier(0); } while (0)

// ---------------------------------------------------------------------------
// One-shot fp32 -> bf16 cast of the five GEMM operands. 1024 elts / block.
// ---------------------------------------------------------------------------
__global__ __launch_bounds__(256)
void cast5(const float* __restrict__ s0, bf16_t* __restrict__ d0, int n0,
           const float* __restrict__ s1, bf16_t* __restrict__ d1, int n1,
           const float* __restrict__ s2, bf16_t* __restrict__ d2, int n2,
           const float* __restrict__ s3, bf16_t* __restrict__ d3, int n3,
           const float* __restrict__ s4, bf16_t* __restrict__ d4)
{
    int bb = blockIdx.x;
    const float* s; bf16_t* d;
    if (bb < n0)              { s = s0; d = d0; }
    else if ((bb -= n0) < n1) { s = s1; d = d1; }
    else if ((bb -= n1) < n2) { s = s2; d = d2; }
    else if ((bb -= n2) < n3) { s = s3; d = d3; }
    else                      { bb -= n3; s = s4; d = d4; }
    const size_t base = (size_t)bb * 1024 + threadIdx.x * 4;
    const f32x4 v = *(const f32x4*)(s + base);
    bf16x4 o;
    o[0] = (bf16_t)v[0]; o[1] = (bf16_t)v[1]; o[2] = (bf16_t)v[2]; o[3] = (bf16_t)v[3];
    *(bf16x4*)(d + base) = o;
}

// ---------------------------------------------------------------------------
// 256x256-tile 8-wave deep-pipelined GEMM (T2+T3+T4+T5 stack), 3-phase/K-tile.
// R2-proven schedule: ds-reads FIRST, stage-prefetch late in phase, boundary
// vmcnt AFTER the P3 MFMA cluster. Do not reorder (R3 regression: -34%).
// ---------------------------------------------------------------------------
#define LOAD_A(MQ) \
    _Pragma("unroll") for (int mf = 0; mf < 4; ++mf) { \
        aF[mf][0] = *(const bf16x8*)(Ab + (aRow + (MQ)*64 + mf*16)*64 + ck0); \
        aF[mf][1] = *(const bf16x8*)(Ab + (aRow + (MQ)*64 + mf*16)*64 + ck1); }

#define LOAD_B(NQ, dst) \
    _Pragma("unroll") for (int nf = 0; nf < 2; ++nf) { \
        dst[nf][0] = *(const bf16x8*)(Bb + (bRow + (NQ)*32 + nf*16)*64 + ck0); \
        dst[nf][1] = *(const bf16x8*)(Bb + (bRow + (NQ)*32 + nf*16)*64 + ck1); }

#define MFMA16(MQ, NQ, bset) \
    __builtin_amdgcn_s_setprio(1); \
    _Pragma("unroll") for (int mf = 0; mf < 4; ++mf) \
    _Pragma("unroll") for (int nf = 0; nf < 2; ++nf) \
    _Pragma("unroll") for (int kk = 0; kk < 2; ++kk) \
        acc[(MQ)*4+mf][(NQ)*2+nf] = __builtin_amdgcn_mfma_f32_16x16x32_bf16( \
            aF[mf][kk], bset[nf][kk], acc[(MQ)*4+mf][(NQ)*2+nf], 0, 0, 0); \
    __builtin_amdgcn_s_setprio(0);

template<int EPI, int SPLITK>
__global__ __launch_bounds__(512, 2)
void gemm256_bt(const bf16_t* __restrict__ A, const bf16_t* __restrict__ Bt,
                const int N, const int K, const int KC,
                bf16_t* __restrict__ o0, bf16_t* __restrict__ o1)
{
    constexpr int TILE = 256 * 64;
    __shared__ __align__(16) bf16_t As[2 * TILE];
    __shared__ __align__(16) bf16_t Bs[2 * TILE];

    const int tid  = threadIdx.x;
    const int lane = tid & 63;
    const int w    = tid >> 6;                 // wave 0..7
    const int wm   = w >> 2, wn = w & 3;       // 2M x 4N wave grid
    const int l16  = lane & 15, quad = lane >> 4;
    const int e7   = l16 & 7;
    const int ck0  = (quad ^ e7) << 3;         // swizzled col (elems), kk=0
    const int ck1  = ck0 ^ 32;                 // kk=1
    const int lr   = lane >> 3, l8 = lane & 7; // staging lane decomposition
    const int swz  = (l8 ^ lr) << 3;           // pre-swizzled global col
    const int m0   = blockIdx.y * 256, n0 = blockIdx.x * 256;
    const int NT   = KC >> 6;

    const int aRow = wm * 128 + l16;
    const int bRow = wn * 64 + l16;

    f32x4 acc[8][4] = {};
    bf16x8 aF[4][2], bLo[2][2], bHi[2][2];

    auto STAGE = [&](int unit, int kt, int d) {
        const bf16_t* g; int rg0; bf16_t* lb; int rbase;
        if (unit <= 1) { g = A;  rg0 = m0; lb = As;
                         rbase = unit * 64 + w * 8; }
        else           { g = Bt; rg0 = n0; lb = Bs;
                         rbase = ((w >> 2) << 6) + ((w & 3) << 3) + ((unit & 1) << 5); }
#pragma unroll
        for (int L = 0; L < 2; ++L) {
            const int rb = rbase + L * 128;
            glds16(g + (size_t)(rg0 + rb + lr) * K + kt * 64 + swz,
                   lb + d * TILE + rb * 64);
        }
    };

    // ---- prologue: tile0 complete + tile1 minus A1 (staged at iter0 P1) ----
    STAGE(2, 0, 0); STAGE(0, 0, 0); STAGE(3, 0, 0); STAGE(1, 0, 0);
    if (NT > 1) { STAGE(2, 1, 1); STAGE(0, 1, 1); STAGE(3, 1, 1); }
    if (NT > 1) asm volatile("s_waitcnt vmcnt(6)" ::: "memory");
    else        asm volatile("s_waitcnt vmcnt(0)" ::: "memory");
    BARRIER();

    for (int i = 0; i < NT; ++i) {
        const int b = i & 1;
        const bf16_t* Ab = As + b * TILE;
        const bf16_t* Bb = Bs + b * TILE;

        // P1: (mlo,nlo) -- load A-lo + B-lo; stage A1(i+1) -> other buf
        LOAD_A(0); LOAD_B(0, bLo);
        if (i + 1 < NT) STAGE(1, i + 1, (i + 1) & 1);
        BARRIER(); DS_WAIT();
        MFMA16(0, 0, bLo);
        __builtin_amdgcn_sched_barrier(0);
        BARRIER();

        // P2: (mlo,nhi) -- load B-hi; stage B0(i+2) -> this buf
        LOAD_B(1, bHi);
        if (i + 2 < NT) STAGE(2, i + 2, b);
        BARRIER(); DS_WAIT();
        MFMA16(0, 1, bHi);
        __builtin_amdgcn_sched_barrier(0);
        BARRIER();

        // P3: (mhi,*) -- load A-hi; stage A0(i+2),B1(i+2); 32 MFMA; boundary
        // vmcnt AFTER the cluster (shadowed), just before the barrier.
        LOAD_A(1);
        if (i + 2 < NT) { STAGE(0, i + 2, b); STAGE(3, i + 2, b); }
        BARRIER(); DS_WAIT();
        MFMA16(1, 1, bHi);
        MFMA16(1, 0, bLo);
        __builtin_amdgcn_sched_barrier(0);
        if (i + 2 < NT) asm volatile("s_waitcnt vmcnt(6)" ::: "memory");
        else            asm volatile("s_waitcnt vmcnt(0)" ::: "memory");
        BARRIER();
    }

    // ---- epilogue: C/D layout col = lane&15, row = quad*4 + reg ----
#pragma unroll
    for (int mf = 0; mf < 8; ++mf)
#pragma unroll
        for (int nf = 0; nf < 4; ++nf)
#pragma unroll
            for (int r = 0; r < 4; ++r) {
                const int gr = m0 + wm * 128 + mf * 16 + quad * 4 + r;
                const int gc = n0 + wn * 64 + nf * 16 + l16;
                const float v = acc[mf][nf][r];
                if (EPI == 1) {
                    if (gc < 2048) o0[(size_t)gr * 2048 + gc] = (bf16_t)v;
                    else           o1[(size_t)gr * 2048 + (gc - 2048)] = (bf16_t)v;
                } else {
                    ((float*)o0)[(size_t)gr * N + gc] = v;
                }
            }
}

// ---------------------------------------------------------------------------
// out_proj GEMM: 64x64 tiles, 1024 blocks = 4 blocks/CU, direct fp32 write.
// NOW with both-sides XOR bank swizzle (rule 21: linear LDS dest + inverse-
// swizzled GLOBAL source col + swizzled read col). The unswizzled [r][64]
// layout had 16-way conflicts on fragment reads (SQ_LDS_BANK_CONFLICT=6.29e6
// in R5/R7); gemm256's identical access shape with this swizzle shows 0.
// ---------------------------------------------------------------------------
__global__ __launch_bounds__(256)
void gemm64(const bf16_t* __restrict__ A, const bf16_t* __restrict__ Bt,
            const int N, const int K, float* __restrict__ out)
{
    __shared__ __align__(16) bf16_t As[64 * 64];
    __shared__ __align__(16) bf16_t Bs[64 * 64];

    const int tid  = threadIdx.x;
    const int lane = tid & 63;
    const int wave = tid >> 6;
    const int wm = wave & 1, wn = wave >> 1;   // 2M x 2N wave grid
    const int m0 = blockIdx.y * 64, n0 = blockIdx.x * 64;
    const int quad = lane >> 4, l16 = lane & 15;
    const int e7   = l16 & 7;
    const int ck0  = (quad ^ e7) << 3;         // swizzled read col, kk=0
    const int ck1  = ck0 ^ 32;                 // kk=1
    const int lr   = lane >> 3, l8 = lane & 7; // staging lane decomposition
    const int swz  = (l8 ^ lr) << 3;           // pre-swizzled global col

    f32x4 acc[2][2] = {};

    for (int k0 = 0; k0 < K; k0 += 64) {
        __syncthreads();
#pragma unroll
        for (int j = 0; j < 2; j++) {
            const int u    = j * 2048 + wave * 512; // elem base (8-row groups)
            const int rowb = u >> 6;                // tile row base (mult of 8)
            glds16(A  + (size_t)(m0 + rowb + lr) * K + k0 + swz, As + u);
            glds16(Bt + (size_t)(n0 + rowb + lr) * K + k0 + swz, Bs + u);
        }
        __syncthreads();

#pragma unroll
        for (int kk = 0; kk < 2; kk++) {
            const int ck = kk ? ck1 : ck0;
            bf16x8 afr[2], bfr[2];
#pragma unroll
            for (int mt = 0; mt < 2; mt++)
                afr[mt] = *(const bf16x8*)(As + (wm * 32 + mt * 16 + l16) * 64 + ck);
#pragma unroll
            for (int nt = 0; nt < 2; nt++)
                bfr[nt] = *(const bf16x8*)(Bs + (wn * 32 + nt * 16 + l16) * 64 + ck);
#pragma unroll
            for (int mt = 0; mt < 2; mt++)
#pragma unroll
                for (int nt = 0; nt < 2; nt++)
                    acc[mt][nt] = __builtin_amdgcn_mfma_f32_16x16x32_bf16(
                        afr[mt], bfr[nt], acc[mt][nt], 0, 0, 0);
        }
    }

    // C/D layout (m89-verified): col = lane&15, row = quad*4 + reg
#pragma unroll
    for (int mt = 0; mt < 2; mt++)
#pragma unroll
        for (int nt = 0; nt < 2; nt++)
#pragma unroll
            for (int r = 0; r < 4; r++) {
                const int gr = m0 + wm * 32 + mt * 16 + quad * 4 + r;
                const int gc = n0 + wn * 32 + nt * 16 + l16;
                out[(size_t)gr * N + gc] = acc[mt][nt][r];
            }
}

// ---------------------------------------------------------------------------
// GEMM: 128x128 tile, 2-barrier structure. (fallback dt_proj EPI 2 only)
// ---------------------------------------------------------------------------
template<int EPI, int SPLITK>
__global__ __launch_bounds__(256)
void gemm_bt(const bf16_t* __restrict__ A, const bf16_t* __restrict__ Bt,
             const int M, const int N, const int K,
             void* __restrict__ o0, void* __restrict__ o1,
             const float* __restrict__ bias)
{
    __shared__ __align__(16) bf16_t As[128 * 64];
    __shared__ __align__(16) bf16_t Bs[128 * 64];

    const int tid  = threadIdx.x;
    const int lane = tid & 63;
    const int wave = tid >> 6;
    const int wm = wave & 1, wn = wave >> 1;
    const int m0 = blockIdx.y * 128, n0 = blockIdx.x * 128;
    const int quad = lane >> 4, l16 = lane & 15;

    f32x4 acc[4][4] = {};

    for (int k0 = 0; k0 < K; k0 += 64) {
        __syncthreads();
#pragma unroll
        for (int j = 0; j < 4; j++) {
            const int u  = wave * 2048 + j * 512;
            const int ue = u + lane * 8;
            const int row = ue >> 6, col = ue & 63;
            glds16(A  + (size_t)(m0 + row) * K + k0 + col, As + u);
            glds16(Bt + (size_t)(n0 + row) * K + k0 + col, Bs + u);
        }
        __syncthreads();

#pragma unroll
        for (int kk = 0; kk < 2; kk++) {
            bf16x8 afr[4], bfr[4];
#pragma unroll
            for (int mt = 0; mt < 4; mt++)
                afr[mt] = *(const bf16x8*)(As + (wm * 64 + mt * 16 + l16) * 64 + kk * 32 + quad * 8);
#pragma unroll
            for (int nt = 0; nt < 4; nt++)
                bfr[nt] = *(const bf16x8*)(Bs + (wn * 64 + nt * 16 + l16) * 64 + kk * 32 + quad * 8);
#pragma unroll
            for (int mt = 0; mt < 4; mt++)
#pragma unroll
                for (int nt = 0; nt < 4; nt++)
                    acc[mt][nt] = __builtin_amdgcn_mfma_f32_16x16x32_bf16(
                        afr[mt], bfr[nt], acc[mt][nt], 0, 0, 0);
        }
    }

#pragma unroll
    for (int mt = 0; mt < 4; mt++)
#pragma unroll
        for (int nt = 0; nt < 4; nt++)
#pragma unroll
            for (int r = 0; r < 4; r++) {
                const int gr = m0 + wm * 64 + mt * 16 + quad * 4 + r;
                const int gc = n0 + wn * 64 + nt * 16 + l16;
                const float v = acc[mt][nt][r];
                if (EPI == 2) {
                    const float t  = v + bias[gc];
                    const float sp = (t > 15.f) ? t : __logf(1.f + __expf(t));
                    ((bf16_t*)o0)[(size_t)gr * 2048 + gc] = (bf16_t)sp;
                } else {
                    ((float*)o0)[(size_t)gr * N + gc] = v;
                }
            }
}

// ---------------------------------------------------------------------------
// FUSED conv+silu -> x_proj -> dt_proj(+softplus). One block = 16 token rows.
// Low-LDS variant (verified R8/R9): x_proj A re-read from global xs (L2-hot).
// ---------------------------------------------------------------------------
__global__ __launch_bounds__(256)
void conv_xproj_dt(const bf16_t* __restrict__ xs_pre,
                   const float* __restrict__ cw, const float* __restrict__ cb,
                   const bf16_t* __restrict__ Wxp, const bf16_t* __restrict__ Wdt,
                   const float* __restrict__ bdt,
                   bf16_t* __restrict__ xs, bf16_t* __restrict__ dt,
                   float* __restrict__ Bm, float* __restrict__ Cm)
{
    __shared__ float red[4][64][25];
    __shared__ __align__(16) bf16_t dtA[16 * 64];     // [row][col], swizzled

    const int tid  = threadIdx.x;
    const int lane = tid & 63, w = tid >> 6;
    const int m0   = blockIdx.x * 16;
    const int l16  = lane & 15, quad = lane >> 4, l8 = lane & 7;
    const int l0   = m0 & 2047;                       // sequence-local base

    // ---- conv + silu: rows m0..m0+15, this thread's 8 channels ----
    {
        const int d0 = tid * 8;
        float w0[8], w1[8], w2[8], w3[8], bs[8];
#pragma unroll
        for (int j = 0; j < 8; j++) {
            const f32x4 wv = *(const f32x4*)(cw + (size_t)(d0 + j) * 4);
            w0[j] = wv[0]; w1[j] = wv[1]; w2[j] = wv[2]; w3[j] = wv[3];
            bs[j] = cb[d0 + j];
        }
        const int r1 = (m0 >= 1) ? m0 - 1 : 0;
        const int r2 = (m0 >= 2) ? m0 - 2 : 0;
        const int r3 = (m0 >= 3) ? m0 - 3 : 0;
        const bf16x8 v1 = *(const bf16x8*)(xs_pre + (size_t)r1 * 2048 + d0);
        const bf16x8 v2 = *(const bf16x8*)(xs_pre + (size_t)r2 * 2048 + d0);
        const bf16x8 v3 = *(const bf16x8*)(xs_pre + (size_t)r3 * 2048 + d0);
        float p1[8], p2[8], p3[8];
#pragma unroll
        for (int j = 0; j < 8; j++) {
            p1[j] = (float)v1[j]; p2[j] = (float)v2[j]; p3[j] = (float)v3[j];
        }
#pragma unroll
        for (int r = 0; r < 16; r++) {
            const int l = l0 + r;
            const float m1 = (l >= 1) ? 1.f : 0.f;
            const float m2 = (l >= 2) ? 1.f : 0.f;
            const float m3 = (l >= 3) ? 1.f : 0.f;
            const bf16x8 v = *(const bf16x8*)(xs_pre + (size_t)(m0 + r) * 2048 + d0);
            bf16x8 o;
#pragma unroll
            for (int j = 0; j < 8; j++) {
                const float cur = (float)v[j];
                float a = bs[j] + w3[j] * cur;
                a += m1 * w2[j] * p1[j];
                a += m2 * w1[j] * p2[j];
                a += m3 * w0[j] * p3[j];
                const float s = a / (1.f + __expf(-a));
                o[j] = (bf16_t)s;
                p3[j] = p2[j]; p2[j] = p1[j]; p1[j] = cur;
            }
            *(bf16x8*)(xs + (size_t)(m0 + r) * 2048 + d0) = o;
        }
    }
    __syncthreads();   // conv writes visible block-wide (workgroup fence)

    // ---- GEMM1 (x_proj): 4-wave split-K over 2048; A from GLOBAL xs ----
    f32x4 acc[6] = {};
    const int kbase = w * 512;
    const bf16_t* ap = xs + (size_t)(m0 + l16) * 2048 + kbase + quad * 8;
    for (int k0 = 0; k0 < 512; k0 += 32) {
        const bf16x8 afr = *(const bf16x8*)(ap + k0);
#pragma unroll
        for (int t = 0; t < 6; t++) {
            const bf16x8 bfr = *(const bf16x8*)(Wxp + (size_t)(t * 16 + l16) * 2048 + kbase + k0 + quad * 8);
            acc[t] = __builtin_amdgcn_mfma_f32_16x16x32_bf16(afr, bfr, acc[t], 0, 0, 0);
        }
    }
#pragma unroll
    for (int t = 0; t < 6; t++)
#pragma unroll
        for (int r = 0; r < 4; r++) red[w][lane][t * 4 + r] = acc[t][r];
    __syncthreads();

    // ---- reduce: wave w builds dtA cols [w*16, +16); wave 0 writes Bm/Cm ----
    {
#pragma unroll
        for (int r = 0; r < 4; r++) {
            const int j = w * 4 + r;
            const float v = red[0][lane][j] + red[1][lane][j]
                          + red[2][lane][j] + red[3][lane][j];
            const int row = quad * 4 + r, col = w * 16 + l16;
            const int g = (col >> 3) ^ (row & 7);
            dtA[row * 64 + g * 8 + (col & 7)] = (bf16_t)v;
        }
        if (w == 0) {
#pragma unroll
            for (int t = 4; t < 6; t++)
#pragma unroll
                for (int r = 0; r < 4; r++) {
                    const int j = t * 4 + r;
                    const float v = red[0][lane][j] + red[1][lane][j]
                                  + red[2][lane][j] + red[3][lane][j];
                    const int gr = m0 + quad * 4 + r;
                    const int gc = t * 16 + l16;
                    if (gc < 80) Bm[(size_t)gr * 16 + (gc - 64)] = v;
                    else         Cm[(size_t)gr * 16 + (gc - 80)] = v;
                }
        }
    }
    __syncthreads();

    // ---- GEMM2 (dt_proj, K=64) + softplus; wave w covers cols [w*512,+512) --
    const bf16x8 a0 = *(const bf16x8*)(dtA + l16 * 64 + (((0 + quad) ^ l8) << 3));
    const bf16x8 a1 = *(const bf16x8*)(dtA + l16 * 64 + (((4 + quad) ^ l8) << 3));
    for (int nt = 0; nt < 32; ++nt) {
        const int nb = w * 512 + nt * 16;
        const bf16x8 b0 = *(const bf16x8*)(Wdt + (size_t)(nb + l16) * 64 + quad * 8);
        const bf16x8 b1 = *(const bf16x8*)(Wdt + (size_t)(nb + l16) * 64 + 32 + quad * 8);
        f32x4 a = {};
        a = __builtin_amdgcn_mfma_f32_16x16x32_bf16(a0, b0, a, 0, 0, 0);
        a = __builtin_amdgcn_mfma_f32_16x16x32_bf16(a1, b1, a, 0, 0, 0);
        const int gc = nb + l16;
        const float bv = bdt[gc];
#pragma unroll
        for (int r = 0; r < 4; r++) {
            const int gr = m0 + quad * 4 + r;
            const float t  = a[r] + bv;
            const float sp = (t > 15.f) ? t : __logf(1.f + __expf(t));
            dt[(size_t)gr * 2048 + gc] = (bf16_t)sp;
        }
    }
}

// ---------------------------------------------------------------------------
// Causal depthwise conv (k=4) + SiLU, vectorized. (fallback path only)
// ---------------------------------------------------------------------------
__global__ __launch_bounds__(256)
void conv_silu(const bf16_t* __restrict__ xs_pre, const float* __restrict__ cw,
               const float* __restrict__ cb, bf16_t* __restrict__ xs)
{
    const int d0 = threadIdx.x * 8;
    const int rg = blockIdx.x * 8;
    float w0[8], w1[8], w2[8], w3[8], bs[8];
#pragma unroll
    for (int j = 0; j < 8; j++) {
        const f32x4 wv = *(const f32x4*)(cw + (size_t)(d0 + j) * 4);
        w0[j] = wv[0]; w1[j] = wv[1]; w2[j] = wv[2]; w3[j] = wv[3];
        bs[j] = cb[d0 + j];
    }
    float p1[8], p2[8], p3[8];
    {
        const int r1 = (rg >= 1) ? rg - 1 : 0;
        const int r2 = (rg >= 2) ? rg - 2 : 0;
        const int r3 = (rg >= 3) ? rg - 3 : 0;
        const bf16x8 v1 = *(const bf16x8*)(xs_pre + (size_t)r1 * 2048 + d0);
        const bf16x8 v2 = *(const bf16x8*)(xs_pre + (size_t)r2 * 2048 + d0);
        const bf16x8 v3 = *(const bf16x8*)(xs_pre + (size_t)r3 * 2048 + d0);
#pragma unroll
        for (int j = 0; j < 8; j++) {
            p1[j] = (float)v1[j]; p2[j] = (float)v2[j]; p3[j] = (float)v3[j];
        }
    }
#pragma unroll
    for (int t = 0; t < 8; t++) {
        const int r = rg + t;
        const int l = r & 2047;
        const float m1 = (l >= 1) ? 1.f : 0.f;
        const float m2 = (l >= 2) ? 1.f : 0.f;
        const float m3 = (l >= 3) ? 1.f : 0.f;
        const bf16x8 v = *(const bf16x8*)(xs_pre + (size_t)r * 2048 + d0);
        bf16x8 o;
#pragma unroll
        for (int j = 0; j < 8; j++) {
            const float cur = (float)v[j];
            float a = bs[j] + w3[j] * cur;
            a += m1 * w2[j] * p1[j];
            a += m2 * w1[j] * p2[j];
            a += m3 * w0[j] * p3[j];
            const float s = a / (1.f + __expf(-a));
            o[j] = (bf16_t)s;
            p3[j] = p2[j]; p2[j] = p1[j]; p1[j] = cur;
        }
        *(bf16x8*)(xs + (size_t)r * 2048 + d0) = o;
    }
}

// ---------------------------------------------------------------------------
// x_proj standalone (fallback path only).
// ---------------------------------------------------------------------------
__global__ __launch_bounds__(256)
void xproj_kernel(const bf16_t* __restrict__ A, const bf16_t* __restrict__ Bt,
                  bf16_t* __restrict__ dtr, float* __restrict__ Bm, float* __restrict__ Cm)
{
    __shared__ float red[4][64][25];
    const int tid  = threadIdx.x;
    const int lane = tid & 63, w = tid >> 6;
    const int m0 = blockIdx.x * 16;
    const int l16 = lane & 15, quad = lane >> 4;
    f32x4 acc[6] = {};

    const int kbase = w * 512;
    const bf16_t* ap = A + (size_t)(m0 + l16) * 2048 + kbase + quad * 8;
    for (int k0 = 0; k0 < 512; k0 += 32) {
        const bf16x8 afr = *(const bf16x8*)(ap + k0);
#pragma unroll
        for (int t = 0; t < 6; t++) {
            const bf16x8 bfr = *(const bf16x8*)(Bt + (size_t)(t * 16 + l16) * 2048 + kbase + k0 + quad * 8);
            acc[t] = __builtin_amdgcn_mfma_f32_16x16x32_bf16(afr, bfr, acc[t], 0, 0, 0);
        }
    }
#pragma unroll
    for (int t = 0; t < 6; t++)
#pragma unroll
        for (int r = 0; r < 4; r++) red[w][lane][t * 4 + r] = acc[t][r];
    __syncthreads();
    if (w == 0) {
#pragma unroll
        for (int t = 0; t < 6; t++)
#pragma unroll
            for (int r = 0; r < 4; r++) {
                const int j = t * 4 + r;
                const float v = red[0][lane][j] + red[1][lane][j]
                              + red[2][lane][j] + red[3][lane][j];
                const int gr = m0 + quad * 4 + r;
                const int gc = t * 16 + l16;
                if (gc < 64)      dtr[(size_t)gr * 64 + gc] = (bf16_t)v;
                else if (gc < 80) Bm[(size_t)gr * 16 + (gc - 64)] = v;
                else              Cm[(size_t)gr * 16 + (gc - 80)] = v;
            }
    }
}

// ---------------------------------------------------------------------------
// Register-state chunked scan. Row-major dt/xs: scalar per-thread loads are
// wave-coalesced (lane i -> channel d+i, consecutive 2B addresses).
// ---------------------------------------------------------------------------
static __device__ __forceinline__ bool fast_check(const float* A_log, int d, float& a1) {
    a1 = -__expf(A_log[(size_t)d * 16]);
    bool ok = true;
#pragma unroll
    for (int n = 1; n < 16; n++) {
        const float an = -__expf(A_log[(size_t)d * 16 + n]);
        const float pn = (float)(n + 1) * a1;
        ok = ok && (fabsf(an - pn) <= 1e-3f * fabsf(pn) + 1e-6f);
    }
    return ok;
}

__global__ __launch_bounds__(256)
void scan1(const bf16_t* __restrict__ dt, const bf16_t* __restrict__ xs,
           const float* __restrict__ Bm, const float* __restrict__ A_log,
           float* __restrict__ sdt_o, bf16_t* __restrict__ Hsum)
{
    const int tid = threadIdx.x;
    const int bi  = blockIdx.x;
    const int c   = bi & 63;
    const int bb  = bi >> 6;
    const int b   = bb >> 3;
    const int d   = (bb & 7) * 256 + tid;
    float a1; const bool fast = fast_check(A_log, d, a1);

    float h[16] = {};
    float s = 0.f;
    const size_t rowbase = (size_t)b * 2048 + c * 32;

    if (fast) {
#pragma unroll 4
        for (int t = 0; t < 32; t++) {
            const size_t ro = (rowbase + t) * 2048 + d;
            const float dtv = (float)dt[ro];
            const float xv  = (float)xs[ro];
            s += dtv;
            const float r = __expf(dtv * a1);
            float rp[16]; rp[0] = r;
#pragma unroll
            for (int n = 1; n < 16; n++) rp[n] = rp[n - 1] * r;
            const float bx = dtv * xv;
            const float* bp = Bm + (rowbase + t) * 16;
#pragma unroll
            for (int n = 0; n < 16; n++) h[n] = fmaf(h[n], rp[n], bx * bp[n]);
        }
    } else {
        for (int t = 0; t < 32; t++) {
            const size_t ro = (rowbase + t) * 2048 + d;
            const float dtv = (float)dt[ro];
            const float xv  = (float)xs[ro];
            s += dtv;
            const float bx = dtv * xv;
            const float* bp = Bm + (rowbase + t) * 16;
#pragma unroll
            for (int n = 0; n < 16; n++) {
                const float an = -__expf(A_log[(size_t)d * 16 + n]);
                h[n] = fmaf(h[n], __expf(dtv * an), bx * bp[n]);
            }
        }
    }
    const size_t sb = (size_t)bi * 256 + tid;
    sdt_o[sb] = s;
    bf16x8 h0, h1;
#pragma unroll
    for (int n = 0; n < 8; n++) { h0[n] = (bf16_t)h[n]; h1[n] = (bf16_t)h[n + 8]; }
    *(bf16x8*)(Hsum + sb * 16)     = h0;
    *(bf16x8*)(Hsum + sb * 16 + 8) = h1;
}

// Inter-chunk exclusive scan, prefetch distance 2.
__global__ __launch_bounds__(256)
void scan2(const float* __restrict__ sdt, bf16_t* __restrict__ Hsum,
           const float* __restrict__ A_log)
{
    const int tid = threadIdx.x;
    const int bb  = blockIdx.x;
    const int d   = (bb & 7) * 256 + tid;
    float a1; const bool fast = fast_check(A_log, d, a1);

    float h[16] = {};
    if (fast) {
        size_t sb = (size_t)(bb * 64) * 256 + tid;
        float sA = sdt[sb];
        bf16x8 hA0 = *(const bf16x8*)(Hsum + sb * 16);
        bf16x8 hA1 = *(const bf16x8*)(Hsum + sb * 16 + 8);
        float sB = 0.f; bf16x8 hB0 = {}, hB1 = {};
        {
            const size_t sb1 = sb + 256;
            sB  = sdt[sb1];
            hB0 = *(const bf16x8*)(Hsum + sb1 * 16);
            hB1 = *(const bf16x8*)(Hsum + sb1 * 16 + 8);
        }
        for (int c = 0; c < 64; c++) {
            float sC = 0.f; bf16x8 hC0 = {}, hC1 = {};
            if (c + 2 < 64) {
                const size_t sb2 = sb + 512;
                sC  = sdt[sb2];
                hC0 = *(const bf16x8*)(Hsum + sb2 * 16);
                hC1 = *(const bf16x8*)(Hsum + sb2 * 16 + 8);
            }
            bf16x8 o0, o1;
#pragma unroll
            for (int n = 0; n < 8; n++) { o0[n] = (bf16_t)h[n]; o1[n] = (bf16_t)h[n + 8]; }
            *(bf16x8*)(Hsum + sb * 16)     = o0;
            *(bf16x8*)(Hsum + sb * 16 + 8) = o1;
            const float r = __expf(sA * a1);
            float rp[16]; rp[0] = r;
#pragma unroll
            for (int n = 1; n < 16; n++) rp[n] = rp[n - 1] * r;
#pragma unroll
            for (int n = 0; n < 16; n++) {
                const float hsv = (n < 8) ? (float)hA0[n] : (float)hA1[n - 8];
                h[n] = fmaf(h[n], rp[n], hsv);
            }
            sb += 256;
            sA = sB; hA0 = hB0; hA1 = hB1;
            sB = sC; hB0 = hC0; hB1 = hC1;
        }
    } else {
        for (int c = 0; c < 64; c++) {
            const size_t sb = ((size_t)(bb * 64 + c) * 256 + tid);
            const float s = sdt[sb];
            bf16x8 hs0 = *(const bf16x8*)(Hsum + sb * 16);
            bf16x8 hs1 = *(const bf16x8*)(Hsum + sb * 16 + 8);
            bf16x8 o0, o1;
#pragma unroll
            for (int n = 0; n < 8; n++) { o0[n] = (bf16_t)h[n]; o1[n] = (bf16_t)h[n + 8]; }
            *(bf16x8*)(Hsum + sb * 16)     = o0;
            *(bf16x8*)(Hsum + sb * 16 + 8) = o1;
#pragma unroll
            for (int n = 0; n < 16; n++) {
                const float an = -__expf(A_log[(size_t)d * 16 + n]);
                const float hsv = (n < 8) ? (float)hs0[n] : (float)hs1[n - 8];
                h[n] = fmaf(h[n], __expf(s * an), hsv);
            }
        }
    }
}

__global__ __launch_bounds__(256)
void scan3(const bf16_t* __restrict__ dt, const bf16_t* __restrict__ xs,
           bf16_t* __restrict__ zy,
           const float* __restrict__ Bm, const float* __restrict__ Cm,
           const float* __restrict__ A_log, const float* __restrict__ Dv,
           const bf16_t* __restrict__ Hseed)
{
    const int tid = threadIdx.x;
    const int bi  = blockIdx.x;
    const int c   = bi & 63;
    const int bb  = bi >> 6;
    const int b   = bb >> 3;
    const int d   = (bb & 7) * 256 + tid;
    float a1; const bool fast = fast_check(A_log, d, a1);
    const float Dd = Dv[d];

    const size_t sb = (size_t)bi * 256 + tid;
    const bf16x8 hs0 = *(const bf16x8*)(Hseed + sb * 16);
    const bf16x8 hs1 = *(const bf16x8*)(Hseed + sb * 16 + 8);
    float h[16];
#pragma unroll
    for (int n = 0; n < 8; n++) { h[n] = (float)hs0[n]; h[n + 8] = (float)hs1[n]; }

    const size_t rowbase = (size_t)b * 2048 + c * 32;

    if (fast) {
#pragma unroll 2
        for (int t = 0; t < 32; t++) {
            const size_t ro = (rowbase + t) * 2048 + d;
            const float dtv = (float)dt[ro];
            const float xv  = (float)xs[ro];
            const float zv  = (float)zy[ro];
            const float r = __expf(dtv * a1);
            float rp[16]; rp[0] = r;
#pragma unroll
            for (int n = 1; n < 16; n++) rp[n] = rp[n - 1] * r;
            const float bx = dtv * xv;
            const float* bp = Bm + (rowbase + t) * 16;
            const float* cp = Cm + (rowbase + t) * 16;
            float y0 = 0.f, y1 = 0.f;
#pragma unroll
            for (int n = 0; n < 16; n += 2) {
                h[n]     = fmaf(h[n],     rp[n],     bx * bp[n]);
                h[n + 1] = fmaf(h[n + 1], rp[n + 1], bx * bp[n + 1]);
                y0 = fmaf(h[n],     cp[n],     y0);
                y1 = fmaf(h[n + 1], cp[n + 1], y1);
            }
            const float yv = (y0 + y1) + xv * Dd;
            const float g  = zv / (1.f + __expf(-zv));
            zy[ro] = (bf16_t)(yv * g);
        }
    } else {
        for (int t = 0; t < 32; t++) {
            const size_t ro = (rowbase + t) * 2048 + d;
            const float dtv = (float)dt[ro];
            const float xv  = (float)xs[ro];
            const float zv  = (float)zy[ro];
            const float bx = dtv * xv;
            const float* bp = Bm + (rowbase + t) * 16;
            const float* cp = Cm + (rowbase + t) * 16;
            float y = 0.f;
#pragma unroll
            for (int n = 0; n < 16; n++) {
                const float an = -__expf(A_log[(size_t)d * 16 + n]);
                h[n] = fmaf(h[n], __expf(dtv * an), bx * bp[n]);
                y = fmaf(h[n], cp[n], y);
            }
            const float yv = y + xv * Dd;
            const float g  = zv / (1.f + __expf(-zv));
            zy[ro] = (bf16_t)(yv * g);
        }
    }
}

// ---------------------------------------------------------------------------
extern "C" void kernel_launch(void* const* d_in, const int* in_sizes, int n_in,
                              void* d_out, int out_size, void* d_ws, size_t ws_size,
                              hipStream_t stream)
{
    const float* x     = (const float*)d_in[0];  // [2,2048,1024]
    const float* W_in  = (const float*)d_in[1];  // [4096,1024]
    const float* convw = (const float*)d_in[2];  // [2048,1,4]
    const float* convb = (const float*)d_in[3];  // [2048]
    const float* W_xp  = (const float*)d_in[4];  // [96,2048]
    const float* W_dt  = (const float*)d_in[5];  // [2048,64]
    const float* b_dt  = (const float*)d_in[6];  // [2048]
    const float* A_log = (const float*)d_in[7];  // [2048,16]
    const float* Dv    = (const float*)d_in[8];  // [2048]
    const float* W_out = (const float*)d_in[9];  // [1024,2048]

    char* ws = (char*)d_ws;
    bf16_t* bufP   = (bf16_t*)(ws + 0);          // xs_pre
    bf16_t* bufZ   = (bf16_t*)(ws + 16777216);   // z -> yg in-place
    bf16_t* bufX   = (bf16_t*)(ws + 33554432);   // xs (conv out), row-major
    bf16_t* W_in_b = (bf16_t*)(ws + 33554432);   // ALIAS: dead before bufX written
    bf16_t* dtr    = (bf16_t*)(ws + 50331648);   // [4096,64] (fallback only)
    float*  Bm     = (float*)(ws + 50855936);    // [4096,16]
    float*  Cm     = (float*)(ws + 51118080);    // [4096,16]
    float*  sdt    = (float*)(ws + 51380224);    // [1024*256]
    bf16_t* Hsum   = (bf16_t*)(ws + 52428800);   // [1024*256*16]
    bf16_t* x_b    = (bf16_t*)(ws + 52428800);   // ALIAS: dead before Hsum written
    bf16_t* W_out_b= (bf16_t*)(ws + 60817408);   // [1024,2048]
    bf16_t* W_xp_b = (bf16_t*)(ws + 65011712);   // [96,2048]
    bf16_t* W_dt_b = (bf16_t*)(ws + 65404928);   // [2048,64]
    bf16_t* dtb    = (bf16_t*)(ws + 65667072);   // dt [4096][2048], 16.78 MB
    const bool fuse = (ws_size >= 82444288ull);  // dtb fits

    // 0) cast all GEMM operands fp32 -> bf16 (one fused kernel)
    cast5<<<dim3(4096 + 4096 + 2048 + 192 + 128), dim3(256), 0, stream>>>(
        x, x_b, 4096, W_in, W_in_b, 4096, W_out, W_out_b, 2048,
        W_xp, W_xp_b, 192, W_dt, W_dt_b);

    // 1) in_proj: xz = x @ W_in^T -> bufP (xs_pre), bufZ (z)  [256^2 pipeline]
    gemm256_bt<1, 1><<<dim3(16, 16), dim3(512), 0, stream>>>(
        x_b, W_in_b, 4096, 1024, 1024, bufP, bufZ);

    bf16_t* dtp = fuse ? dtb : bufP;   // where scan reads dt from
    if (fuse) {
        // 2-4) conv+silu -> xs ; x_proj -> Bm,Cm ; dt_proj+softplus -> dtb
        conv_xproj_dt<<<dim3(256), dim3(256), 0, stream>>>(
            bufP, convw, convb, W_xp_b, W_dt_b, b_dt, bufX, dtb, Bm, Cm);
    } else {
        conv_silu<<<dim3(512), dim3(256), 0, stream>>>(bufP, convw, convb, bufX);
        xproj_kernel<<<dim3(256), dim3(256), 0, stream>>>(bufX, W_xp_b, dtr, Bm, Cm);
        gemm_bt<2, 1><<<dim3(16, 32), dim3(256), 0, stream>>>(
            dtr, W_dt_b, 4096, 2048, 64, (void*)bufP, nullptr, b_dt);
    }

    // 5) register-state chunked scan + skip + gate -> bufZ in place
    scan1<<<dim3(1024), dim3(256), 0, stream>>>(dtp, bufX, Bm, A_log, sdt, Hsum);
    scan2<<<dim3(16),   dim3(256), 0, stream>>>(sdt, Hsum, A_log);
    scan3<<<dim3(1024), dim3(256), 0, stream>>>(dtp, bufX, bufZ, Bm, Cm, A_log, Dv, Hsum);

    // 6) out_proj: 64x64 tiles, 1024 blocks = 4/CU, direct fp32 write,
    //    both-sides XOR bank swizzle (kills the 6.29e6 16-way conflicts).
    gemm64<<<dim3(16, 64), dim3(256), 0, stream>>>(
        bufZ, W_out_b, 1024, 2048, (float*)d_out);
}